// Round 4
// baseline (13539.429 us; speedup 1.0000x reference)
//
#include <hip/hip_runtime.h>
#include <hip/hip_bf16.h>

#define S_LEN 2048
#define NHEAD 16
#define NOPE 128
#define ROPE 64
#define HD 192   // nope + rope

// Generic C[M,N] = A[M,K] @ B[K,N]; A,B,C f32 row-major.
// fp32 accumulate. 64x64 tile, BK=16, 256 threads, 4x4 per thread.
// Requires M%64==0, N%64==0, K%16==0 (true for all shapes here).
__global__ __launch_bounds__(256) void gemm_k(const float* __restrict__ A,
                                              const float* __restrict__ B,
                                              float* __restrict__ C,
                                              int M, int N, int K) {
  __shared__ float As[16][65];               // [kk][m]
  __shared__ __align__(16) float Bs[16][68]; // [kk][n] ; 68 keeps rows 16B-aligned
  const int tid = threadIdx.x;
  const int tx = tid & 15, ty = tid >> 4;
  const int m0 = blockIdx.y * 64, n0 = blockIdx.x * 64;
  float acc[4][4] = {};
  for (int k0 = 0; k0 < K; k0 += 16) {
    for (int i = tid; i < 64 * 16; i += 256) {
      int r = i >> 4, kk = i & 15;
      As[kk][r] = A[(size_t)(m0 + r) * K + (k0 + kk)];
    }
    for (int i = tid; i < 16 * 64; i += 256) {
      int kk = i >> 6, j = i & 63;
      Bs[kk][j] = B[(size_t)(k0 + kk) * N + (n0 + j)];
    }
    __syncthreads();
#pragma unroll
    for (int kk = 0; kk < 16; ++kk) {
      float a0 = As[kk][ty * 4 + 0];
      float a1 = As[kk][ty * 4 + 1];
      float a2 = As[kk][ty * 4 + 2];
      float a3 = As[kk][ty * 4 + 3];
      const float4 bv = *(const float4*)&Bs[kk][tx * 4];
      acc[0][0] += a0 * bv.x; acc[0][1] += a0 * bv.y; acc[0][2] += a0 * bv.z; acc[0][3] += a0 * bv.w;
      acc[1][0] += a1 * bv.x; acc[1][1] += a1 * bv.y; acc[1][2] += a1 * bv.z; acc[1][3] += a1 * bv.w;
      acc[2][0] += a2 * bv.x; acc[2][1] += a2 * bv.y; acc[2][2] += a2 * bv.z; acc[2][3] += a2 * bv.w;
      acc[3][0] += a3 * bv.x; acc[3][1] += a3 * bv.y; acc[3][2] += a3 * bv.z; acc[3][3] += a3 * bv.w;
    }
    __syncthreads();
  }
#pragma unroll
  for (int r = 0; r < 4; ++r)
#pragma unroll
    for (int c = 0; c < 4; ++c)
      C[(size_t)(m0 + ty * 4 + r) * N + (n0 + tx * 4 + c)] = acc[r][c];
}

// One block per row. y = x * rsqrt(mean(x^2) + 1e-5) * w. In-place safe.
__global__ __launch_bounds__(256) void rmsnorm_k(const float* __restrict__ in, int in_stride,
                                                 float* __restrict__ out, int out_stride,
                                                 const float* __restrict__ w, int L) {
  const int row = blockIdx.x;
  const int tid = threadIdx.x;
  const float* ip = in + (size_t)row * in_stride;
  float* op = out + (size_t)row * out_stride;
  const int nper = L >> 8;  // L/256 (6 or 2)
  float r[6];
  float ss = 0.f;
  for (int j = 0; j < nper; ++j) {
    r[j] = ip[tid + (j << 8)];
    ss += r[j] * r[j];
  }
  for (int off = 32; off; off >>= 1) ss += __shfl_down(ss, off);
  __shared__ float wsum[4];
  __shared__ float scale_s;
  if ((tid & 63) == 0) wsum[tid >> 6] = ss;
  __syncthreads();
  if (tid == 0) {
    float t = wsum[0] + wsum[1] + wsum[2] + wsum[3];
    scale_s = rsqrtf(t / (float)L + 1e-5f);
  }
  __syncthreads();
  const float sc = scale_s;
  for (int j = 0; j < nper; ++j)
    op[tid + (j << 8)] = r[j] * sc * w[tid + (j << 8)];
}

// RoPE: in-place on qall rope dims (per head), and kvd[:,512:576] -> krope.
// Interleaved pairs: (x0,x1)=(even,odd); o0=x0*c-x1*s, o1=x0*s+x1*c.
__global__ __launch_bounds__(512) void rope_k(float* __restrict__ qall,
                                              const float* __restrict__ kvd,
                                              float* __restrict__ krope,
                                              const float* __restrict__ cosb,
                                              const float* __restrict__ sinb) {
  const int row = blockIdx.x;           // b*S + s
  const int s = row & (S_LEN - 1);
  const int tid = threadIdx.x;
  const int d = tid & 31, h = tid >> 5; // 16 heads x 32 pairs
  const float c = cosb[s * 32 + d];
  const float sn = sinb[s * 32 + d];
  float* qb = qall + (size_t)row * 3072 + h * HD + NOPE;
  float x0 = qb[2 * d], x1 = qb[2 * d + 1];
  qb[2 * d]     = x0 * c - x1 * sn;
  qb[2 * d + 1] = x0 * sn + x1 * c;
  if (tid < 32) {
    const float* kb = kvd + (size_t)row * 576 + 512;
    float y0 = kb[2 * d], y1 = kb[2 * d + 1];
    krope[(size_t)row * 64 + 2 * d]     = y0 * c - y1 * sn;
    krope[(size_t)row * 64 + 2 * d + 1] = y0 * sn + y1 * c;
  }
}

// Causal online-softmax attention. One block (256 thr) per (b,h,q) row.
// K staged in LDS in 64-key chunks (stride 196 floats: 192%32==0 would be 16-way conflicted).
#define KCHUNK 64
#define KSTR 196
__global__ __launch_bounds__(256) void attn_k(const float* __restrict__ qall,
                                              const float* __restrict__ kvu,
                                              const float* __restrict__ krope,
                                              float* __restrict__ outp) {
  const int q = blockIdx.x & (S_LEN - 1);
  const int h = (blockIdx.x >> 11) & 15;
  const int b = blockIdx.x >> 15;
  const int tid = threadIdx.x;
  __shared__ float qv[HD];
  __shared__ float ks[KCHUNK * KSTR];
  __shared__ float pv[KCHUNK];
  __shared__ float acc[NOPE];
  __shared__ float m_s, l_s, alpha_s;
  const size_t rowq = (size_t)(b * S_LEN + q);
  for (int i = tid; i < HD; i += 256) qv[i] = qall[rowq * 3072 + h * HD + i];
  if (tid < NOPE) acc[tid] = 0.f;
  if (tid == 0) { m_s = -INFINITY; l_s = 0.f; }
  __syncthreads();
  const float scale = 0.07216878364870323f;  // 1/sqrt(192)
  for (int j0 = 0; j0 <= q; j0 += KCHUNK) {
    // stage K chunk: k = [kvu nope part | krope]
    for (int i = tid; i < KCHUNK * HD; i += 256) {
      int jj = i / HD, d = i - jj * HD;
      size_t rk = (size_t)(b * S_LEN + j0 + jj);
      float v = (d < NOPE) ? kvu[rk * 4096 + h * 256 + d]
                           : krope[rk * 64 + (d - NOPE)];
      ks[jj * KSTR + d] = v;
    }
    __syncthreads();
    // dots: 4 threads per key, 48 dims each
    const int jj = tid >> 2, l4 = tid & 3;
    const float* kr = &ks[jj * KSTR + l4 * 48];
    const float* qr = &qv[l4 * 48];
    float part = 0.f;
#pragma unroll
    for (int dd = 0; dd < 48; ++dd) part += qr[dd] * kr[dd];
    part += __shfl_down(part, 2, 4);
    part += __shfl_down(part, 1, 4);
    if (l4 == 0) pv[jj] = ((j0 + jj) <= q) ? part * scale : -INFINITY;
    __syncthreads();
    // online softmax update (first wave only; tids 0..63 are one wave)
    if (tid < 64) {
      float sv = pv[tid];
      float mx = sv;
      for (int off = 32; off; off >>= 1) mx = fmaxf(mx, __shfl_down(mx, off));
      mx = __shfl(mx, 0);
      float m_old = m_s;
      float m_new = fmaxf(m_old, mx);
      float pj = expf(sv - m_new);  // -inf -> 0
      pv[tid] = pj;
      float sum = pj;
      for (int off = 32; off; off >>= 1) sum += __shfl_down(sum, off);
      if (tid == 0) {
        float alpha = expf(m_old - m_new);
        l_s = l_s * alpha + sum;
        m_s = m_new;
        alpha_s = alpha;
      }
    }
    __syncthreads();
    // P @ V (V read coalesced from L2)
    if (tid < NOPE) {
      float a = acc[tid] * alpha_s;
      size_t base = (size_t)(b * S_LEN + j0) * 4096 + h * 256 + NOPE + tid;
#pragma unroll 4
      for (int j2 = 0; j2 < KCHUNK; ++j2)
        a += pv[j2] * kvu[base + (size_t)j2 * 4096];
      acc[tid] = a;
    }
    __syncthreads();
  }
  if (tid < NOPE) outp[rowq * 2048 + h * NOPE + tid] = acc[tid] / l_s;
}

extern "C" void kernel_launch(void* const* d_in, const int* in_sizes, int n_in,
                              void* d_out, int out_size, void* d_ws, size_t ws_size,
                              hipStream_t stream) {
  const float* x        = (const float*)d_in[0];
  const float* wd_q     = (const float*)d_in[1];
  const float* wu_q     = (const float*)d_in[2];
  const float* q_norm_w = (const float*)d_in[3];
  const float* wd_kv    = (const float*)d_in[4];
  const float* wu_kv    = (const float*)d_in[5];
  const float* kv_norm_w= (const float*)d_in[6];
  const float* wo       = (const float*)d_in[7];
  const float* cosb     = (const float*)d_in[8];
  const float* sinb     = (const float*)d_in[9];
  float* out = (float*)d_out;   // reference output dtype is float32

  char* ws = (char*)d_ws;
  float* cq    = (float*)(ws + 0);          // 4096x1536 f32 (25165824 B)
  float* kvd   = (float*)(ws + 25165824);   // 4096x576  f32 ( 9437184 B)
  float* ckvn  = (float*)(ws + 34603008);   // 4096x512  f32 ( 8388608 B)
  float* qall  = (float*)(ws + 42991616);   // 4096x3072 f32 (50331648 B)
  float* kvu   = (float*)(ws + 93323264);   // 4096x4096 f32 (67108864 B)
  float* krope = (float*)(ws + 160432128);  // 4096x64   f32 ( 1048576 B)
  float* aout  = (float*)(ws + 161480704);  // 4096x2048 f32 (33554432 B)
  // total 195035136 B

  const int M = 2 * S_LEN;  // 4096 rows
  dim3 blk(256);

  // cq = x @ wd_q ; kvd = x @ wd_kv
  gemm_k<<<dim3(1536 / 64, M / 64), blk, 0, stream>>>(x, wd_q, cq, M, 1536, 2048);
  gemm_k<<<dim3(576 / 64, M / 64), blk, 0, stream>>>(x, wd_kv, kvd, M, 576, 2048);
  // rmsnorms
  rmsnorm_k<<<M, 256, 0, stream>>>(cq, 1536, cq, 1536, q_norm_w, 1536);
  rmsnorm_k<<<M, 256, 0, stream>>>(kvd, 576, ckvn, 512, kv_norm_w, 512);
  // up-projections
  gemm_k<<<dim3(3072 / 64, M / 64), blk, 0, stream>>>(cq, wu_q, qall, M, 3072, 1536);
  gemm_k<<<dim3(4096 / 64, M / 64), blk, 0, stream>>>(ckvn, wu_kv, kvu, M, 4096, 512);
  // rope (q in-place; k_rope extracted from kvd)
  rope_k<<<M, 512, 0, stream>>>(qall, kvd, krope, cosb, sinb);
  // attention
  attn_k<<<2 * NHEAD * S_LEN, 256, 0, stream>>>(qall, kvu, krope, aout);
  // output projection (f32 out)
  gemm_k<<<dim3(2048 / 64, M / 64), blk, 0, stream>>>(aout, wo, out, M, 2048, 2048);
}

// Round 5
// 4366.349 us; speedup vs baseline: 3.1009x; 3.1009x over previous
//
#include <hip/hip_runtime.h>
#include <hip/hip_bf16.h>

#define S_LEN 2048
#define NHEAD 16
#define NOPE 128
#define ROPE 64
#define HD 192   // nope + rope

// ---------------- GEMM (unchanged from round 3) ----------------
__global__ __launch_bounds__(256) void gemm_k(const float* __restrict__ A,
                                              const float* __restrict__ B,
                                              float* __restrict__ C,
                                              int M, int N, int K) {
  __shared__ float As[16][65];
  __shared__ __align__(16) float Bs[16][68];
  const int tid = threadIdx.x;
  const int tx = tid & 15, ty = tid >> 4;
  const int m0 = blockIdx.y * 64, n0 = blockIdx.x * 64;
  float acc[4][4] = {};
  for (int k0 = 0; k0 < K; k0 += 16) {
    for (int i = tid; i < 64 * 16; i += 256) {
      int r = i >> 4, kk = i & 15;
      As[kk][r] = A[(size_t)(m0 + r) * K + (k0 + kk)];
    }
    for (int i = tid; i < 16 * 64; i += 256) {
      int kk = i >> 6, j = i & 63;
      Bs[kk][j] = B[(size_t)(k0 + kk) * N + (n0 + j)];
    }
    __syncthreads();
#pragma unroll
    for (int kk = 0; kk < 16; ++kk) {
      float a0 = As[kk][ty * 4 + 0];
      float a1 = As[kk][ty * 4 + 1];
      float a2 = As[kk][ty * 4 + 2];
      float a3 = As[kk][ty * 4 + 3];
      const float4 bv = *(const float4*)&Bs[kk][tx * 4];
      acc[0][0] += a0 * bv.x; acc[0][1] += a0 * bv.y; acc[0][2] += a0 * bv.z; acc[0][3] += a0 * bv.w;
      acc[1][0] += a1 * bv.x; acc[1][1] += a1 * bv.y; acc[1][2] += a1 * bv.z; acc[1][3] += a1 * bv.w;
      acc[2][0] += a2 * bv.x; acc[2][1] += a2 * bv.y; acc[2][2] += a2 * bv.z; acc[2][3] += a2 * bv.w;
      acc[3][0] += a3 * bv.x; acc[3][1] += a3 * bv.y; acc[3][2] += a3 * bv.z; acc[3][3] += a3 * bv.w;
    }
    __syncthreads();
  }
#pragma unroll
  for (int r = 0; r < 4; ++r)
#pragma unroll
    for (int c = 0; c < 4; ++c)
      C[(size_t)(m0 + ty * 4 + r) * N + (n0 + tx * 4 + c)] = acc[r][c];
}

// ---------------- RMSNorm (unchanged) ----------------
__global__ __launch_bounds__(256) void rmsnorm_k(const float* __restrict__ in, int in_stride,
                                                 float* __restrict__ out, int out_stride,
                                                 const float* __restrict__ w, int L) {
  const int row = blockIdx.x;
  const int tid = threadIdx.x;
  const float* ip = in + (size_t)row * in_stride;
  float* op = out + (size_t)row * out_stride;
  const int nper = L >> 8;
  float r[6];
  float ss = 0.f;
  for (int j = 0; j < nper; ++j) {
    r[j] = ip[tid + (j << 8)];
    ss += r[j] * r[j];
  }
  for (int off = 32; off; off >>= 1) ss += __shfl_down(ss, off);
  __shared__ float wsum[4];
  __shared__ float scale_s;
  if ((tid & 63) == 0) wsum[tid >> 6] = ss;
  __syncthreads();
  if (tid == 0) {
    float t = wsum[0] + wsum[1] + wsum[2] + wsum[3];
    scale_s = rsqrtf(t / (float)L + 1e-5f);
  }
  __syncthreads();
  const float sc = scale_s;
  for (int j = 0; j < nper; ++j)
    op[tid + (j << 8)] = r[j] * sc * w[tid + (j << 8)];
}

// ---------------- RoPE (unchanged) ----------------
__global__ __launch_bounds__(512) void rope_k(float* __restrict__ qall,
                                              const float* __restrict__ kvd,
                                              float* __restrict__ krope,
                                              const float* __restrict__ cosb,
                                              const float* __restrict__ sinb) {
  const int row = blockIdx.x;
  const int s = row & (S_LEN - 1);
  const int tid = threadIdx.x;
  const int d = tid & 31, h = tid >> 5;
  const float c = cosb[s * 32 + d];
  const float sn = sinb[s * 32 + d];
  float* qb = qall + (size_t)row * 3072 + h * HD + NOPE;
  float x0 = qb[2 * d], x1 = qb[2 * d + 1];
  qb[2 * d]     = x0 * c - x1 * sn;
  qb[2 * d + 1] = x0 * sn + x1 * c;
  if (tid < 32) {
    const float* kb = kvd + (size_t)row * 576 + 512;
    float y0 = kb[2 * d], y1 = kb[2 * d + 1];
    krope[(size_t)row * 64 + 2 * d]     = y0 * c - y1 * sn;
    krope[(size_t)row * 64 + 2 * d + 1] = y0 * sn + y1 * c;
  }
}

// ---------------- Flash attention, 64-q tile per block ----------------
// Grid: b*512 + h*32 + tile (1024 blocks), 256 threads.
// LDS: Qbf (bf16, transposed [d][q]) + Kt (f32, transposed [d][k]) + Ps + stats
//      = 60.8 KB -> 2 blocks/CU. V read from L2 in PV phase (1 MB/bh, resident).
#define QT 64
#define KC 32
__global__ __launch_bounds__(256) void attn_k(const float* __restrict__ qall,
                                              const float* __restrict__ kvu,
                                              const float* __restrict__ krope,
                                              float* __restrict__ outp) {
  const int bx = blockIdx.x;
  const int tile = bx & 31;
  const int h = (bx >> 5) & 15;
  const int b = bx >> 9;
  const int q0 = tile * QT;
  const int t = threadIdx.x;

  __shared__ unsigned short Qbf[192][68];  // stride 68: short4 reads 8B-aligned
  __shared__ float Kt[192][34];            // stride 34: float2 reads, conflict-free
  __shared__ float Ps[64][36];
  __shared__ float m_sh[64], l_sh[64], al_sh[64];

  const size_t rowq0 = (size_t)(b * S_LEN + q0);

  // stage Q (once), transposed, bf16 (round-to-nearest-even)
  for (int i = t; i < 64 * 48; i += 256) {
    int qq = i / 48, dc = i % 48;
    const float4 v = *(const float4*)&qall[(rowq0 + qq) * 3072 + h * HD + dc * 4];
    const float vf[4] = {v.x, v.y, v.z, v.w};
#pragma unroll
    for (int l = 0; l < 4; ++l) {
      unsigned int u = __float_as_uint(vf[l]);
      Qbf[dc * 4 + l][qq] = (unsigned short)((u + 0x7FFFu + ((u >> 16) & 1u)) >> 16);
    }
  }
  if (t < 64) { m_sh[t] = -INFINITY; l_sh[t] = 0.f; }

  const int tx = t & 15, ty = t >> 4;
  float oacc[4][8];
#pragma unroll
  for (int i = 0; i < 4; ++i)
#pragma unroll
    for (int j = 0; j < 8; ++j) oacc[i][j] = 0.f;

  const float scale = 0.07216878364870323f;  // 1/sqrt(192)
  const int nchunk = (q0 + QT - 1) / KC + 1;

  for (int c = 0; c < nchunk; ++c) {
    const int j0 = c * KC;
    __syncthreads();  // protect Kt/Ps from previous iteration's readers
    // ---- stage K chunk transposed: d<128 from kvu, d>=128 from krope ----
    for (int i = t; i < KC * 32; i += 256) {          // nope: 32 rows x 32 float4
      int kk = i >> 5, dc = i & 31;
      const float4 v = *(const float4*)&kvu[(size_t)(b * S_LEN + j0 + kk) * 4096 + h * 256 + dc * 4];
      Kt[dc * 4 + 0][kk] = v.x; Kt[dc * 4 + 1][kk] = v.y;
      Kt[dc * 4 + 2][kk] = v.z; Kt[dc * 4 + 3][kk] = v.w;
    }
    for (int i = t; i < KC * 16; i += 256) {          // rope: 32 rows x 16 float4
      int kk = i >> 4, dc = i & 15;
      const float4 v = *(const float4*)&krope[(size_t)(b * S_LEN + j0 + kk) * 64 + dc * 4];
      Kt[128 + dc * 4 + 0][kk] = v.x; Kt[128 + dc * 4 + 1][kk] = v.y;
      Kt[128 + dc * 4 + 2][kk] = v.z; Kt[128 + dc * 4 + 3][kk] = v.w;
    }
    __syncthreads();
    // ---- scores: 4q x 2k per thread ----
    float sacc[4][2] = {};
#pragma unroll 4
    for (int d = 0; d < 192; ++d) {
      const uint2 qu = *(const uint2*)&Qbf[d][ty * 4];
      const float qf0 = __uint_as_float(qu.x << 16);
      const float qf1 = __uint_as_float(qu.x & 0xFFFF0000u);
      const float qf2 = __uint_as_float(qu.y << 16);
      const float qf3 = __uint_as_float(qu.y & 0xFFFF0000u);
      const float2 kv = *(const float2*)&Kt[d][tx * 2];
      sacc[0][0] += qf0 * kv.x; sacc[0][1] += qf0 * kv.y;
      sacc[1][0] += qf1 * kv.x; sacc[1][1] += qf1 * kv.y;
      sacc[2][0] += qf2 * kv.x; sacc[2][1] += qf2 * kv.y;
      sacc[3][0] += qf3 * kv.x; sacc[3][1] += qf3 * kv.y;
    }
#pragma unroll
    for (int i = 0; i < 4; ++i) {
      const int row = ty * 4 + i;
      float2 sv;
      sv.x = ((j0 + tx * 2)     <= (q0 + row)) ? sacc[i][0] * scale : -1e30f;
      sv.y = ((j0 + tx * 2 + 1) <= (q0 + row)) ? sacc[i][1] * scale : -1e30f;
      *(float2*)&Ps[row][tx * 2] = sv;
    }
    __syncthreads();
    // ---- online softmax: 4 threads per row, width-4 shuffles ----
    {
      const int row = t >> 2, l4 = t & 3;
      float4 s0 = *(const float4*)&Ps[row][l4 * 8];
      float4 s1 = *(const float4*)&Ps[row][l4 * 8 + 4];
      float mx = fmaxf(fmaxf(fmaxf(s0.x, s0.y), fmaxf(s0.z, s0.w)),
                       fmaxf(fmaxf(s1.x, s1.y), fmaxf(s1.z, s1.w)));
      mx = fmaxf(mx, __shfl_down(mx, 2, 4));
      mx = fmaxf(mx, __shfl_down(mx, 1, 4));
      mx = __shfl(mx, 0, 4);
      const float m_old = m_sh[row];
      const float m_new = fmaxf(m_old, mx);
      const float a = __expf(m_old - m_new);
      s0.x = __expf(s0.x - m_new); s0.y = __expf(s0.y - m_new);
      s0.z = __expf(s0.z - m_new); s0.w = __expf(s0.w - m_new);
      s1.x = __expf(s1.x - m_new); s1.y = __expf(s1.y - m_new);
      s1.z = __expf(s1.z - m_new); s1.w = __expf(s1.w - m_new);
      float sum = s0.x + s0.y + s0.z + s0.w + s1.x + s1.y + s1.z + s1.w;
      sum += __shfl_down(sum, 2, 4);
      sum += __shfl_down(sum, 1, 4);
      if (l4 == 0) {
        m_sh[row] = m_new;
        al_sh[row] = a;
        l_sh[row] = l_sh[row] * a + sum;
      }
      *(float4*)&Ps[row][l4 * 8] = s0;
      *(float4*)&Ps[row][l4 * 8 + 4] = s1;
    }
    __syncthreads();
    // ---- PV: rescale + accumulate; V coalesced from L2 ----
    {
      const float a0 = al_sh[ty * 4 + 0];
      const float a1 = al_sh[ty * 4 + 1];
      const float a2 = al_sh[ty * 4 + 2];
      const float a3 = al_sh[ty * 4 + 3];
#pragma unroll
      for (int j = 0; j < 8; ++j) {
        oacc[0][j] *= a0; oacc[1][j] *= a1; oacc[2][j] *= a2; oacc[3][j] *= a3;
      }
      const size_t vbase = (size_t)(b * S_LEN + j0) * 4096 + h * 256 + 128 + tx * 4;
#pragma unroll 4
      for (int j = 0; j < KC; ++j) {
        const float4 v0 = *(const float4*)&kvu[vbase + (size_t)j * 4096];
        const float4 v1 = *(const float4*)&kvu[vbase + (size_t)j * 4096 + 64];
        const float p0 = Ps[ty * 4 + 0][j];
        const float p1 = Ps[ty * 4 + 1][j];
        const float p2 = Ps[ty * 4 + 2][j];
        const float p3 = Ps[ty * 4 + 3][j];
        oacc[0][0] += p0 * v0.x; oacc[0][1] += p0 * v0.y; oacc[0][2] += p0 * v0.z; oacc[0][3] += p0 * v0.w;
        oacc[0][4] += p0 * v1.x; oacc[0][5] += p0 * v1.y; oacc[0][6] += p0 * v1.z; oacc[0][7] += p0 * v1.w;
        oacc[1][0] += p1 * v0.x; oacc[1][1] += p1 * v0.y; oacc[1][2] += p1 * v0.z; oacc[1][3] += p1 * v0.w;
        oacc[1][4] += p1 * v1.x; oacc[1][5] += p1 * v1.y; oacc[1][6] += p1 * v1.z; oacc[1][7] += p1 * v1.w;
        oacc[2][0] += p2 * v0.x; oacc[2][1] += p2 * v0.y; oacc[2][2] += p2 * v0.z; oacc[2][3] += p2 * v0.w;
        oacc[2][4] += p2 * v1.x; oacc[2][5] += p2 * v1.y; oacc[2][6] += p2 * v1.z; oacc[2][7] += p2 * v1.w;
        oacc[3][0] += p3 * v0.x; oacc[3][1] += p3 * v0.y; oacc[3][2] += p3 * v0.z; oacc[3][3] += p3 * v0.w;
        oacc[3][4] += p3 * v1.x; oacc[3][5] += p3 * v1.y; oacc[3][6] += p3 * v1.z; oacc[3][7] += p3 * v1.w;
      }
    }
  }
  __syncthreads();
#pragma unroll
  for (int i = 0; i < 4; ++i) {
    const int row = ty * 4 + i;
    const float inv = 1.0f / l_sh[row];
    float4 o0 = {oacc[i][0] * inv, oacc[i][1] * inv, oacc[i][2] * inv, oacc[i][3] * inv};
    float4 o1 = {oacc[i][4] * inv, oacc[i][5] * inv, oacc[i][6] * inv, oacc[i][7] * inv};
    *(float4*)&outp[(rowq0 + row) * 2048 + h * 128 + tx * 4] = o0;
    *(float4*)&outp[(rowq0 + row) * 2048 + h * 128 + 64 + tx * 4] = o1;
  }
}

extern "C" void kernel_launch(void* const* d_in, const int* in_sizes, int n_in,
                              void* d_out, int out_size, void* d_ws, size_t ws_size,
                              hipStream_t stream) {
  const float* x        = (const float*)d_in[0];
  const float* wd_q     = (const float*)d_in[1];
  const float* wu_q     = (const float*)d_in[2];
  const float* q_norm_w = (const float*)d_in[3];
  const float* wd_kv    = (const float*)d_in[4];
  const float* wu_kv    = (const float*)d_in[5];
  const float* kv_norm_w= (const float*)d_in[6];
  const float* wo       = (const float*)d_in[7];
  const float* cosb     = (const float*)d_in[8];
  const float* sinb     = (const float*)d_in[9];
  float* out = (float*)d_out;

  char* ws = (char*)d_ws;
  float* cq    = (float*)(ws + 0);          // 4096x1536 f32
  float* kvd   = (float*)(ws + 25165824);   // 4096x576  f32
  float* ckvn  = (float*)(ws + 34603008);   // 4096x512  f32
  float* qall  = (float*)(ws + 42991616);   // 4096x3072 f32
  float* kvu   = (float*)(ws + 93323264);   // 4096x4096 f32
  float* krope = (float*)(ws + 160432128);  // 4096x64   f32
  float* aout  = (float*)(ws + 161480704);  // 4096x2048 f32

  const int M = 2 * S_LEN;  // 4096 rows
  dim3 blk(256);

  gemm_k<<<dim3(1536 / 64, M / 64), blk, 0, stream>>>(x, wd_q, cq, M, 1536, 2048);
  gemm_k<<<dim3(576 / 64, M / 64), blk, 0, stream>>>(x, wd_kv, kvd, M, 576, 2048);
  rmsnorm_k<<<M, 256, 0, stream>>>(cq, 1536, cq, 1536, q_norm_w, 1536);
  rmsnorm_k<<<M, 256, 0, stream>>>(kvd, 576, ckvn, 512, kv_norm_w, 512);
  gemm_k<<<dim3(3072 / 64, M / 64), blk, 0, stream>>>(cq, wu_q, qall, M, 3072, 1536);
  gemm_k<<<dim3(4096 / 64, M / 64), blk, 0, stream>>>(ckvn, wu_kv, kvu, M, 4096, 512);
  rope_k<<<M, 512, 0, stream>>>(qall, kvd, krope, cosb, sinb);
  attn_k<<<2 * NHEAD * (S_LEN / QT), 256, 0, stream>>>(qall, kvu, krope, aout);
  gemm_k<<<dim3(2048 / 64, M / 64), blk, 0, stream>>>(aout, wo, out, M, 2048, 2048);
}

// Round 6
// 2157.241 us; speedup vs baseline: 6.2763x; 2.0240x over previous
//
#include <hip/hip_runtime.h>
#include <hip/hip_bf16.h>

#define S_LEN 2048
#define NHEAD 16
#define NOPE 128
#define ROPE 64
#define HD 192   // nope + rope

typedef unsigned short ushort_t;
typedef __attribute__((ext_vector_type(8))) short short8;
typedef __attribute__((ext_vector_type(4))) float f32x4;

__device__ __forceinline__ unsigned short f2bf(float f) {
  unsigned int u = __float_as_uint(f);
  return (unsigned short)((u + 0x7FFFu + ((u >> 16) & 1u)) >> 16);
}
__device__ __forceinline__ float bf2f(unsigned short s) {
  return __uint_as_float(((unsigned int)s) << 16);
}

// ---------------- transpose + cast: B f32 [K][N] -> Bt bf16 [Npad][K] ----------------
// N, K multiples of 32. Blocks with n0 >= N write zeros (pad rows).
__global__ __launch_bounds__(256) void transpose_cast_k(const float* __restrict__ B,
                                                        ushort_t* __restrict__ Bt,
                                                        int K, int N) {
  __shared__ float tile[32][33];
  const int tx = threadIdx.x & 31, ty = threadIdx.x >> 5;  // 32 x 8
  const int n0 = blockIdx.x * 32, k0 = blockIdx.y * 32;
  if (n0 >= N) {
#pragma unroll
    for (int r = 0; r < 4; ++r)
      Bt[(size_t)(n0 + ty + 8 * r) * K + k0 + tx] = 0;
    return;
  }
#pragma unroll
  for (int r = 0; r < 4; ++r)
    tile[ty + 8 * r][tx] = B[(size_t)(k0 + ty + 8 * r) * N + n0 + tx];
  __syncthreads();
#pragma unroll
  for (int r = 0; r < 4; ++r)
    Bt[(size_t)(n0 + ty + 8 * r) * K + k0 + tx] = f2bf(tile[tx][ty + 8 * r]);
}

// ---------------- MFMA GEMM ----------------
// C[M,N] (f32, row stride ldc) = A[M,K] @ Bt[N,K]^T.
// A: bf16 [M][K] (or f32 if A_IS_F32). Bt: bf16 [N][K] (pre-transposed weights).
// 128x128 tile, BK=32, 256 threads = 4 waves in 2x2, each wave 64x64 via
// 4x4 grid of 16x16x32 MFMAs. LDS rows stride 32 bf16 (64 B): frag
// ds_read_b128s hit 8 distinct bank-quads -> conflict-free.
template<bool A_IS_F32>
__global__ __launch_bounds__(256) void mfma_gemm(const void* __restrict__ Av,
                                                 const ushort_t* __restrict__ Bt,
                                                 float* __restrict__ C,
                                                 int M, int N, int K, int ldc) {
  __shared__ ushort_t As[128 * 32];
  __shared__ ushort_t Bs[128 * 32];
  const int tid = threadIdx.x;
  const int lane = tid & 63;
  const int wave = tid >> 6;
  const int wm = wave & 1, wn = wave >> 1;
  const int m0 = blockIdx.y * 128, n0 = blockIdx.x * 128;
  const int l15 = lane & 15, quad = lane >> 4;

  f32x4 acc[4][4] = {};

  // staging decomposition: item in [0,512): m = item>>2, kc = item&3 (8 bf16 per item)
  const int it0 = tid, it1 = tid + 256;
  const int ma0 = it0 >> 2, kc0 = it0 & 3;
  const int ma1 = it1 >> 2, kc1 = it1 & 3;

  for (int k0 = 0; k0 < K; k0 += 32) {
    if (A_IS_F32) {
      const float* Af = (const float*)Av;
      {
        const float4 v0 = *(const float4*)&Af[(size_t)(m0 + ma0) * K + k0 + kc0 * 8];
        const float4 v1 = *(const float4*)&Af[(size_t)(m0 + ma0) * K + k0 + kc0 * 8 + 4];
        union { uint4 u; ushort_t s[8]; } pk;
        pk.s[0] = f2bf(v0.x); pk.s[1] = f2bf(v0.y); pk.s[2] = f2bf(v0.z); pk.s[3] = f2bf(v0.w);
        pk.s[4] = f2bf(v1.x); pk.s[5] = f2bf(v1.y); pk.s[6] = f2bf(v1.z); pk.s[7] = f2bf(v1.w);
        *(uint4*)&As[it0 * 8] = pk.u;
      }
      {
        const float4 v0 = *(const float4*)&Af[(size_t)(m0 + ma1) * K + k0 + kc1 * 8];
        const float4 v1 = *(const float4*)&Af[(size_t)(m0 + ma1) * K + k0 + kc1 * 8 + 4];
        union { uint4 u; ushort_t s[8]; } pk;
        pk.s[0] = f2bf(v0.x); pk.s[1] = f2bf(v0.y); pk.s[2] = f2bf(v0.z); pk.s[3] = f2bf(v0.w);
        pk.s[4] = f2bf(v1.x); pk.s[5] = f2bf(v1.y); pk.s[6] = f2bf(v1.z); pk.s[7] = f2bf(v1.w);
        *(uint4*)&As[it1 * 8] = pk.u;
      }
    } else {
      const ushort_t* Ab = (const ushort_t*)Av;
      *(uint4*)&As[it0 * 8] = *(const uint4*)&Ab[(size_t)(m0 + ma0) * K + k0 + kc0 * 8];
      *(uint4*)&As[it1 * 8] = *(const uint4*)&Ab[(size_t)(m0 + ma1) * K + k0 + kc1 * 8];
    }
    *(uint4*)&Bs[it0 * 8] = *(const uint4*)&Bt[(size_t)(n0 + ma0) * K + k0 + kc0 * 8];
    *(uint4*)&Bs[it1 * 8] = *(const uint4*)&Bt[(size_t)(n0 + ma1) * K + k0 + kc1 * 8];
    __syncthreads();

    short8 af[4], bf[4];
#pragma unroll
    for (int i = 0; i < 4; ++i)
      af[i] = *(const short8*)&As[(wm * 64 + i * 16 + l15) * 32 + quad * 8];
#pragma unroll
    for (int j = 0; j < 4; ++j)
      bf[j] = *(const short8*)&Bs[(wn * 64 + j * 16 + l15) * 32 + quad * 8];
#pragma unroll
    for (int i = 0; i < 4; ++i)
#pragma unroll
      for (int j = 0; j < 4; ++j)
        acc[i][j] = __builtin_amdgcn_mfma_f32_16x16x32_bf16(af[i], bf[j], acc[i][j], 0, 0, 0);
    __syncthreads();
  }

  // epilogue: D row = quad*4 + r, col = l15 (doc-verified mapping)
#pragma unroll
  for (int i = 0; i < 4; ++i)
#pragma unroll
    for (int r = 0; r < 4; ++r) {
      const size_t rg = (size_t)(m0 + wm * 64 + i * 16 + quad * 4 + r);
#pragma unroll
      for (int j = 0; j < 4; ++j)
        C[rg * ldc + n0 + wn * 64 + j * 16 + l15] = acc[i][j][r];
    }
}

// ---------------- RMSNorm: f32 in -> bf16 out ----------------
__global__ __launch_bounds__(256) void rmsnorm_k(const float* __restrict__ in, int in_stride,
                                                 ushort_t* __restrict__ out, int out_stride,
                                                 const float* __restrict__ w, int L) {
  const int row = blockIdx.x;
  const int tid = threadIdx.x;
  const float* ip = in + (size_t)row * in_stride;
  ushort_t* op = out + (size_t)row * out_stride;
  const int nper = L >> 8;
  float r[6];
  float ss = 0.f;
  for (int j = 0; j < nper; ++j) {
    r[j] = ip[tid + (j << 8)];
    ss += r[j] * r[j];
  }
  for (int off = 32; off; off >>= 1) ss += __shfl_down(ss, off);
  __shared__ float wsum[4];
  __shared__ float scale_s;
  if ((tid & 63) == 0) wsum[tid >> 6] = ss;
  __syncthreads();
  if (tid == 0) {
    float t = wsum[0] + wsum[1] + wsum[2] + wsum[3];
    scale_s = rsqrtf(t / (float)L + 1e-5f);
  }
  __syncthreads();
  const float sc = scale_s;
  for (int j = 0; j < nper; ++j)
    op[tid + (j << 8)] = f2bf(r[j] * sc * w[tid + (j << 8)]);
}

// ---------------- RoPE (kvd now stride 640) ----------------
__global__ __launch_bounds__(512) void rope_k(float* __restrict__ qall,
                                              const float* __restrict__ kvd,
                                              float* __restrict__ krope,
                                              const float* __restrict__ cosb,
                                              const float* __restrict__ sinb) {
  const int row = blockIdx.x;
  const int s = row & (S_LEN - 1);
  const int tid = threadIdx.x;
  const int d = tid & 31, h = tid >> 5;
  const float c = cosb[s * 32 + d];
  const float sn = sinb[s * 32 + d];
  float* qb = qall + (size_t)row * 3072 + h * HD + NOPE;
  float x0 = qb[2 * d], x1 = qb[2 * d + 1];
  qb[2 * d]     = x0 * c - x1 * sn;
  qb[2 * d + 1] = x0 * sn + x1 * c;
  if (tid < 32) {
    const float* kb = kvd + (size_t)row * 640 + 512;
    float y0 = kb[2 * d], y1 = kb[2 * d + 1];
    krope[(size_t)row * 64 + 2 * d]     = y0 * c - y1 * sn;
    krope[(size_t)row * 64 + 2 * d + 1] = y0 * sn + y1 * c;
  }
}

// ---------------- Flash attention (unchanged except bf16 output) ----------------
#define QT 64
#define KC 32
__global__ __launch_bounds__(256) void attn_k(const float* __restrict__ qall,
                                              const float* __restrict__ kvu,
                                              const float* __restrict__ krope,
                                              ushort_t* __restrict__ outp) {
  const int bx = blockIdx.x;
  const int tile = bx & 31;
  const int h = (bx >> 5) & 15;
  const int b = bx >> 9;
  const int q0 = tile * QT;
  const int t = threadIdx.x;

  __shared__ unsigned short Qbf[192][68];
  __shared__ float Kt[192][34];
  __shared__ float Ps[64][36];
  __shared__ float m_sh[64], l_sh[64], al_sh[64];

  const size_t rowq0 = (size_t)(b * S_LEN + q0);

  for (int i = t; i < 64 * 48; i += 256) {
    int qq = i / 48, dc = i % 48;
    const float4 v = *(const float4*)&qall[(rowq0 + qq) * 3072 + h * HD + dc * 4];
    const float vf[4] = {v.x, v.y, v.z, v.w};
#pragma unroll
    for (int l = 0; l < 4; ++l)
      Qbf[dc * 4 + l][qq] = f2bf(vf[l]);
  }
  if (t < 64) { m_sh[t] = -INFINITY; l_sh[t] = 0.f; }

  const int tx = t & 15, ty = t >> 4;
  float oacc[4][8];
#pragma unroll
  for (int i = 0; i < 4; ++i)
#pragma unroll
    for (int j = 0; j < 8; ++j) oacc[i][j] = 0.f;

  const float scale = 0.07216878364870323f;
  const int nchunk = (q0 + QT - 1) / KC + 1;

  for (int c = 0; c < nchunk; ++c) {
    const int j0 = c * KC;
    __syncthreads();
    for (int i = t; i < KC * 32; i += 256) {
      int kk = i >> 5, dc = i & 31;
      const float4 v = *(const float4*)&kvu[(size_t)(b * S_LEN + j0 + kk) * 4096 + h * 256 + dc * 4];
      Kt[dc * 4 + 0][kk] = v.x; Kt[dc * 4 + 1][kk] = v.y;
      Kt[dc * 4 + 2][kk] = v.z; Kt[dc * 4 + 3][kk] = v.w;
    }
    for (int i = t; i < KC * 16; i += 256) {
      int kk = i >> 4, dc = i & 15;
      const float4 v = *(const float4*)&krope[(size_t)(b * S_LEN + j0 + kk) * 64 + dc * 4];
      Kt[128 + dc * 4 + 0][kk] = v.x; Kt[128 + dc * 4 + 1][kk] = v.y;
      Kt[128 + dc * 4 + 2][kk] = v.z; Kt[128 + dc * 4 + 3][kk] = v.w;
    }
    __syncthreads();
    float sacc[4][2] = {};
#pragma unroll 4
    for (int d = 0; d < 192; ++d) {
      const uint2 qu = *(const uint2*)&Qbf[d][ty * 4];
      const float qf0 = __uint_as_float(qu.x << 16);
      const float qf1 = __uint_as_float(qu.x & 0xFFFF0000u);
      const float qf2 = __uint_as_float(qu.y << 16);
      const float qf3 = __uint_as_float(qu.y & 0xFFFF0000u);
      const float2 kv = *(const float2*)&Kt[d][tx * 2];
      sacc[0][0] += qf0 * kv.x; sacc[0][1] += qf0 * kv.y;
      sacc[1][0] += qf1 * kv.x; sacc[1][1] += qf1 * kv.y;
      sacc[2][0] += qf2 * kv.x; sacc[2][1] += qf2 * kv.y;
      sacc[3][0] += qf3 * kv.x; sacc[3][1] += qf3 * kv.y;
    }
#pragma unroll
    for (int i = 0; i < 4; ++i) {
      const int row = ty * 4 + i;
      float2 sv;
      sv.x = ((j0 + tx * 2)     <= (q0 + row)) ? sacc[i][0] * scale : -1e30f;
      sv.y = ((j0 + tx * 2 + 1) <= (q0 + row)) ? sacc[i][1] * scale : -1e30f;
      *(float2*)&Ps[row][tx * 2] = sv;
    }
    __syncthreads();
    {
      const int row = t >> 2, l4 = t & 3;
      float4 s0 = *(const float4*)&Ps[row][l4 * 8];
      float4 s1 = *(const float4*)&Ps[row][l4 * 8 + 4];
      float mx = fmaxf(fmaxf(fmaxf(s0.x, s0.y), fmaxf(s0.z, s0.w)),
                       fmaxf(fmaxf(s1.x, s1.y), fmaxf(s1.z, s1.w)));
      mx = fmaxf(mx, __shfl_down(mx, 2, 4));
      mx = fmaxf(mx, __shfl_down(mx, 1, 4));
      mx = __shfl(mx, 0, 4);
      const float m_old = m_sh[row];
      const float m_new = fmaxf(m_old, mx);
      const float a = __expf(m_old - m_new);
      s0.x = __expf(s0.x - m_new); s0.y = __expf(s0.y - m_new);
      s0.z = __expf(s0.z - m_new); s0.w = __expf(s0.w - m_new);
      s1.x = __expf(s1.x - m_new); s1.y = __expf(s1.y - m_new);
      s1.z = __expf(s1.z - m_new); s1.w = __expf(s1.w - m_new);
      float sum = s0.x + s0.y + s0.z + s0.w + s1.x + s1.y + s1.z + s1.w;
      sum += __shfl_down(sum, 2, 4);
      sum += __shfl_down(sum, 1, 4);
      if (l4 == 0) {
        m_sh[row] = m_new;
        al_sh[row] = a;
        l_sh[row] = l_sh[row] * a + sum;
      }
      *(float4*)&Ps[row][l4 * 8] = s0;
      *(float4*)&Ps[row][l4 * 8 + 4] = s1;
    }
    __syncthreads();
    {
      const float a0 = al_sh[ty * 4 + 0];
      const float a1 = al_sh[ty * 4 + 1];
      const float a2 = al_sh[ty * 4 + 2];
      const float a3 = al_sh[ty * 4 + 3];
#pragma unroll
      for (int j = 0; j < 8; ++j) {
        oacc[0][j] *= a0; oacc[1][j] *= a1; oacc[2][j] *= a2; oacc[3][j] *= a3;
      }
      const size_t vbase = (size_t)(b * S_LEN + j0) * 4096 + h * 256 + 128 + tx * 4;
#pragma unroll 4
      for (int j = 0; j < KC; ++j) {
        const float4 v0 = *(const float4*)&kvu[vbase + (size_t)j * 4096];
        const float4 v1 = *(const float4*)&kvu[vbase + (size_t)j * 4096 + 64];
        const float p0 = Ps[ty * 4 + 0][j];
        const float p1 = Ps[ty * 4 + 1][j];
        const float p2 = Ps[ty * 4 + 2][j];
        const float p3 = Ps[ty * 4 + 3][j];
        oacc[0][0] += p0 * v0.x; oacc[0][1] += p0 * v0.y; oacc[0][2] += p0 * v0.z; oacc[0][3] += p0 * v0.w;
        oacc[0][4] += p0 * v1.x; oacc[0][5] += p0 * v1.y; oacc[0][6] += p0 * v1.z; oacc[0][7] += p0 * v1.w;
        oacc[1][0] += p1 * v0.x; oacc[1][1] += p1 * v0.y; oacc[1][2] += p1 * v0.z; oacc[1][3] += p1 * v0.w;
        oacc[1][4] += p1 * v1.x; oacc[1][5] += p1 * v1.y; oacc[1][6] += p1 * v1.z; oacc[1][7] += p1 * v1.w;
        oacc[2][0] += p2 * v0.x; oacc[2][1] += p2 * v0.y; oacc[2][2] += p2 * v0.z; oacc[2][3] += p2 * v0.w;
        oacc[2][4] += p2 * v1.x; oacc[2][5] += p2 * v1.y; oacc[2][6] += p2 * v1.z; oacc[2][7] += p2 * v1.w;
        oacc[3][0] += p3 * v0.x; oacc[3][1] += p3 * v0.y; oacc[3][2] += p3 * v0.z; oacc[3][3] += p3 * v0.w;
        oacc[3][4] += p3 * v1.x; oacc[3][5] += p3 * v1.y; oacc[3][6] += p3 * v1.z; oacc[3][7] += p3 * v1.w;
      }
    }
  }
  __syncthreads();
#pragma unroll
  for (int i = 0; i < 4; ++i) {
    const int row = ty * 4 + i;
    const float inv = 1.0f / l_sh[row];
    ushort4 o0, o1;
    o0.x = f2bf(oacc[i][0] * inv); o0.y = f2bf(oacc[i][1] * inv);
    o0.z = f2bf(oacc[i][2] * inv); o0.w = f2bf(oacc[i][3] * inv);
    o1.x = f2bf(oacc[i][4] * inv); o1.y = f2bf(oacc[i][5] * inv);
    o1.z = f2bf(oacc[i][6] * inv); o1.w = f2bf(oacc[i][7] * inv);
    *(ushort4*)&outp[(rowq0 + row) * 2048 + h * 128 + tx * 4] = o0;
    *(ushort4*)&outp[(rowq0 + row) * 2048 + h * 128 + 64 + tx * 4] = o1;
  }
}

extern "C" void kernel_launch(void* const* d_in, const int* in_sizes, int n_in,
                              void* d_out, int out_size, void* d_ws, size_t ws_size,
                              hipStream_t stream) {
  const float* x        = (const float*)d_in[0];
  const float* wd_q     = (const float*)d_in[1];
  const float* wu_q     = (const float*)d_in[2];
  const float* q_norm_w = (const float*)d_in[3];
  const float* wd_kv    = (const float*)d_in[4];
  const float* wu_kv    = (const float*)d_in[5];
  const float* kv_norm_w= (const float*)d_in[6];
  const float* wo       = (const float*)d_in[7];
  const float* cosb     = (const float*)d_in[8];
  const float* sinb     = (const float*)d_in[9];
  float* out = (float*)d_out;

  // liveness-packed workspace (178.8 MB total):
  char* ws = (char*)d_ws;
  float*    qall  = (float*)(ws + 0);            // 4096x3072 f32; cq (4096x1536 f32) aliases @0 (dead before qall)
  float*    cq    = (float*)(ws + 0);
  float*    kvu   = (float*)(ws + 50331648);     // 4096x4096 f32
  ushort_t* cqn   = (ushort_t*)(ws + 117440512); // 4096x1536 bf16
  float*    kvd   = (float*)(ws + 130023424);    // 4096x640 f32 (dead after rope)
  ushort_t* ckvn  = (ushort_t*)(ws + 140509184); // 4096x512 bf16 (dead after kvu gemm)
  ushort_t* aoutb = (ushort_t*)(ws + 130023424); // 4096x2048 bf16, aliases kvd+ckvn (attn runs after both dead)
  float*    krope = (float*)(ws + 146800640);    // 4096x64 f32
  ushort_t* wdqt  = (ushort_t*)(ws + 147849216); // 1536x2048 bf16
  ushort_t* wdkvt = (ushort_t*)(ws + 154140672); // 640x2048 bf16 (576 valid + 64 zero rows)
  ushort_t* wuqt  = (ushort_t*)(ws + 156762112); // 3072x1536 bf16
  ushort_t* wukvt = (ushort_t*)(ws + 166199296); // 4096x512 bf16
  ushort_t* wot   = (ushort_t*)(ws + 170393600); // 2048x2048 bf16

  const int M = 2 * S_LEN;  // 4096
  dim3 blk(256);

  // weight transposes + casts (f32 [K][N] -> bf16 [N][K])
  transpose_cast_k<<<dim3(1536 / 32, 2048 / 32), blk, 0, stream>>>(wd_q, wdqt, 2048, 1536);
  transpose_cast_k<<<dim3(640 / 32, 2048 / 32), blk, 0, stream>>>(wd_kv, wdkvt, 2048, 576);
  transpose_cast_k<<<dim3(3072 / 32, 1536 / 32), blk, 0, stream>>>(wu_q, wuqt, 1536, 3072);
  transpose_cast_k<<<dim3(4096 / 32, 512 / 32), blk, 0, stream>>>(wu_kv, wukvt, 512, 4096);
  transpose_cast_k<<<dim3(2048 / 32, 2048 / 32), blk, 0, stream>>>(wo, wot, 2048, 2048);

  // down-projections (A = x, f32)
  mfma_gemm<true><<<dim3(1536 / 128, M / 128), blk, 0, stream>>>(x, wdqt, cq, M, 1536, 2048, 1536);
  mfma_gemm<true><<<dim3(640 / 128, M / 128), blk, 0, stream>>>(x, wdkvt, kvd, M, 640, 2048, 640);
  // rmsnorms (f32 -> bf16)
  rmsnorm_k<<<M, 256, 0, stream>>>(cq, 1536, cqn, 1536, q_norm_w, 1536);
  rmsnorm_k<<<M, 256, 0, stream>>>(kvd, 640, ckvn, 512, kv_norm_w, 512);
  // up-projections (A = bf16)
  mfma_gemm<false><<<dim3(3072 / 128, M / 128), blk, 0, stream>>>(cqn, wuqt, qall, M, 3072, 1536, 3072);
  mfma_gemm<false><<<dim3(4096 / 128, M / 128), blk, 0, stream>>>(ckvn, wukvt, kvu, M, 4096, 512, 4096);
  // rope
  rope_k<<<M, 512, 0, stream>>>(qall, kvd, krope, cosb, sinb);
  // attention -> bf16
  attn_k<<<2 * NHEAD * (S_LEN / QT), 256, 0, stream>>>(qall, kvu, krope, aoutb);
  // output projection (A = bf16 attn out, C = f32 d_out)
  mfma_gemm<false><<<dim3(2048 / 128, M / 128), blk, 0, stream>>>(aoutb, wot, out, M, 2048, 2048, 2048);
}

// Round 7
// 768.120 us; speedup vs baseline: 17.6267x; 2.8085x over previous
//
#include <hip/hip_runtime.h>
#include <hip/hip_bf16.h>

#define S_LEN 2048
#define NHEAD 16
#define NOPE 128
#define ROPE 64
#define HD 192   // nope + rope

typedef unsigned short ushort_t;
typedef __attribute__((ext_vector_type(8))) short short8;
typedef __attribute__((ext_vector_type(4))) float f32x4;

__device__ __forceinline__ unsigned short f2bf(float f) {
  unsigned int u = __float_as_uint(f);
  return (unsigned short)((u + 0x7FFFu + ((u >> 16) & 1u)) >> 16);
}

// ---------------- transpose + cast: B f32 [K][N] -> Bt bf16 [Npad][K] ----------------
__global__ __launch_bounds__(256) void transpose_cast_k(const float* __restrict__ B,
                                                        ushort_t* __restrict__ Bt,
                                                        int K, int N) {
  __shared__ float tile[32][33];
  const int tx = threadIdx.x & 31, ty = threadIdx.x >> 5;  // 32 x 8
  const int n0 = blockIdx.x * 32, k0 = blockIdx.y * 32;
  if (n0 >= N) {
#pragma unroll
    for (int r = 0; r < 4; ++r)
      Bt[(size_t)(n0 + ty + 8 * r) * K + k0 + tx] = 0;
    return;
  }
#pragma unroll
  for (int r = 0; r < 4; ++r)
    tile[ty + 8 * r][tx] = B[(size_t)(k0 + ty + 8 * r) * N + n0 + tx];
  __syncthreads();
#pragma unroll
  for (int r = 0; r < 4; ++r)
    Bt[(size_t)(n0 + ty + 8 * r) * K + k0 + tx] = f2bf(tile[tx][ty + 8 * r]);
}

// ---------------- MFMA GEMM (unchanged from round 6, verified) ----------------
template<bool A_IS_F32>
__global__ __launch_bounds__(256) void mfma_gemm(const void* __restrict__ Av,
                                                 const ushort_t* __restrict__ Bt,
                                                 float* __restrict__ C,
                                                 int M, int N, int K, int ldc) {
  __shared__ ushort_t As[128 * 32];
  __shared__ ushort_t Bs[128 * 32];
  const int tid = threadIdx.x;
  const int lane = tid & 63;
  const int wave = tid >> 6;
  const int wm = wave & 1, wn = wave >> 1;
  const int m0 = blockIdx.y * 128, n0 = blockIdx.x * 128;
  const int l15 = lane & 15, quad = lane >> 4;

  f32x4 acc[4][4] = {};

  const int it0 = tid, it1 = tid + 256;
  const int ma0 = it0 >> 2, kc0 = it0 & 3;
  const int ma1 = it1 >> 2, kc1 = it1 & 3;

  for (int k0 = 0; k0 < K; k0 += 32) {
    if (A_IS_F32) {
      const float* Af = (const float*)Av;
      {
        const float4 v0 = *(const float4*)&Af[(size_t)(m0 + ma0) * K + k0 + kc0 * 8];
        const float4 v1 = *(const float4*)&Af[(size_t)(m0 + ma0) * K + k0 + kc0 * 8 + 4];
        union { uint4 u; ushort_t s[8]; } pk;
        pk.s[0] = f2bf(v0.x); pk.s[1] = f2bf(v0.y); pk.s[2] = f2bf(v0.z); pk.s[3] = f2bf(v0.w);
        pk.s[4] = f2bf(v1.x); pk.s[5] = f2bf(v1.y); pk.s[6] = f2bf(v1.z); pk.s[7] = f2bf(v1.w);
        *(uint4*)&As[it0 * 8] = pk.u;
      }
      {
        const float4 v0 = *(const float4*)&Af[(size_t)(m0 + ma1) * K + k0 + kc1 * 8];
        const float4 v1 = *(const float4*)&Af[(size_t)(m0 + ma1) * K + k0 + kc1 * 8 + 4];
        union { uint4 u; ushort_t s[8]; } pk;
        pk.s[0] = f2bf(v0.x); pk.s[1] = f2bf(v0.y); pk.s[2] = f2bf(v0.z); pk.s[3] = f2bf(v0.w);
        pk.s[4] = f2bf(v1.x); pk.s[5] = f2bf(v1.y); pk.s[6] = f2bf(v1.z); pk.s[7] = f2bf(v1.w);
        *(uint4*)&As[it1 * 8] = pk.u;
      }
    } else {
      const ushort_t* Ab = (const ushort_t*)Av;
      *(uint4*)&As[it0 * 8] = *(const uint4*)&Ab[(size_t)(m0 + ma0) * K + k0 + kc0 * 8];
      *(uint4*)&As[it1 * 8] = *(const uint4*)&Ab[(size_t)(m0 + ma1) * K + k0 + kc1 * 8];
    }
    *(uint4*)&Bs[it0 * 8] = *(const uint4*)&Bt[(size_t)(n0 + ma0) * K + k0 + kc0 * 8];
    *(uint4*)&Bs[it1 * 8] = *(const uint4*)&Bt[(size_t)(n0 + ma1) * K + k0 + kc1 * 8];
    __syncthreads();

    short8 af[4], bf[4];
#pragma unroll
    for (int i = 0; i < 4; ++i)
      af[i] = *(const short8*)&As[(wm * 64 + i * 16 + l15) * 32 + quad * 8];
#pragma unroll
    for (int j = 0; j < 4; ++j)
      bf[j] = *(const short8*)&Bs[(wn * 64 + j * 16 + l15) * 32 + quad * 8];
#pragma unroll
    for (int i = 0; i < 4; ++i)
#pragma unroll
      for (int j = 0; j < 4; ++j)
        acc[i][j] = __builtin_amdgcn_mfma_f32_16x16x32_bf16(af[i], bf[j], acc[i][j], 0, 0, 0);
    __syncthreads();
  }

#pragma unroll
  for (int i = 0; i < 4; ++i)
#pragma unroll
    for (int r = 0; r < 4; ++r) {
      const size_t rg = (size_t)(m0 + wm * 64 + i * 16 + quad * 4 + r);
#pragma unroll
      for (int j = 0; j < 4; ++j)
        C[rg * ldc + n0 + wn * 64 + j * 16 + l15] = acc[i][j][r];
    }
}

// ---------------- RMSNorm: f32 in -> bf16 out ----------------
__global__ __launch_bounds__(256) void rmsnorm_k(const float* __restrict__ in, int in_stride,
                                                 ushort_t* __restrict__ out, int out_stride,
                                                 const float* __restrict__ w, int L) {
  const int row = blockIdx.x;
  const int tid = threadIdx.x;
  const float* ip = in + (size_t)row * in_stride;
  ushort_t* op = out + (size_t)row * out_stride;
  const int nper = L >> 8;
  float r[6];
  float ss = 0.f;
  for (int j = 0; j < nper; ++j) {
    r[j] = ip[tid + (j << 8)];
    ss += r[j] * r[j];
  }
  for (int off = 32; off; off >>= 1) ss += __shfl_down(ss, off);
  __shared__ float wsum[4];
  __shared__ float scale_s;
  if ((tid & 63) == 0) wsum[tid >> 6] = ss;
  __syncthreads();
  if (tid == 0) {
    float t = wsum[0] + wsum[1] + wsum[2] + wsum[3];
    scale_s = rsqrtf(t / (float)L + 1e-5f);
  }
  __syncthreads();
  const float sc = scale_s;
  for (int j = 0; j < nper; ++j)
    op[tid + (j << 8)] = f2bf(r[j] * sc * w[tid + (j << 8)]);
}

// ---------------- RoPE ----------------
__global__ __launch_bounds__(512) void rope_k(float* __restrict__ qall,
                                              const float* __restrict__ kvd,
                                              float* __restrict__ krope,
                                              const float* __restrict__ cosb,
                                              const float* __restrict__ sinb) {
  const int row = blockIdx.x;
  const int s = row & (S_LEN - 1);
  const int tid = threadIdx.x;
  const int d = tid & 31, h = tid >> 5;
  const float c = cosb[s * 32 + d];
  const float sn = sinb[s * 32 + d];
  float* qb = qall + (size_t)row * 3072 + h * HD + NOPE;
  float x0 = qb[2 * d], x1 = qb[2 * d + 1];
  qb[2 * d]     = x0 * c - x1 * sn;
  qb[2 * d + 1] = x0 * sn + x1 * c;
  if (tid < 32) {
    const float* kb = kvd + (size_t)row * 640 + 512;
    float y0 = kb[2 * d], y1 = kb[2 * d + 1];
    krope[(size_t)row * 64 + 2 * d]     = y0 * c - y1 * sn;
    krope[(size_t)row * 64 + 2 * d + 1] = y0 * sn + y1 * c;
  }
}

// ---------------- MFMA flash attention ----------------
// Grid 512 = b(2) x h(16) x tile(16); 256 threads = 4 waves x 32 q-rows.
// Q frags in registers; K bf16 [key][200] LDS; V^T bf16 [vd][72] LDS;
// P per-wave-private [32][72] LDS. All LDS row strides ≡ 4 dwords mod 32
// -> 2-way (free) bank aliasing on ds_read_b128 fragment reads.
#define QT 128
#define KC 64
__global__ __launch_bounds__(256, 2) void attn_k(const float* __restrict__ qall,
                                                 const float* __restrict__ kvu,
                                                 const float* __restrict__ krope,
                                                 ushort_t* __restrict__ outp) {
  const int bx = blockIdx.x;
  const int tile = bx & 15;
  const int h = (bx >> 4) & 15;
  const int b = bx >> 8;
  const int q0 = tile * QT;
  const int tid = threadIdx.x;
  const int lane = tid & 63;
  const int wq = tid >> 6;
  const int l15 = lane & 15, quad = lane >> 4;

  __shared__ ushort_t Kb[64 * 200];
  __shared__ ushort_t Vt[128 * 72];
  __shared__ ushort_t Pb[4][32 * 72];

  const int qbase = q0 + wq * 32;
  const size_t growq = (size_t)b * S_LEN + qbase;

  // Q fragments (bf16) in registers: [mt][ks]
  short8 qf[2][6];
#pragma unroll
  for (int mt = 0; mt < 2; ++mt)
#pragma unroll
    for (int ks = 0; ks < 6; ++ks) {
      const float* src = &qall[(growq + mt * 16 + l15) * 3072 + h * HD + ks * 32 + quad * 8];
      const float4 v0 = *(const float4*)src;
      const float4 v1 = *(const float4*)(src + 4);
      union { short8 s8; ushort_t u[8]; } pk;
      pk.u[0] = f2bf(v0.x); pk.u[1] = f2bf(v0.y); pk.u[2] = f2bf(v0.z); pk.u[3] = f2bf(v0.w);
      pk.u[4] = f2bf(v1.x); pk.u[5] = f2bf(v1.y); pk.u[6] = f2bf(v1.z); pk.u[7] = f2bf(v1.w);
      qf[mt][ks] = pk.s8;
    }

  f32x4 oacc[2][8] = {};
  float mrow[2][4], lrow[2][4];
  int q_r[2][4];
#pragma unroll
  for (int mt = 0; mt < 2; ++mt)
#pragma unroll
    for (int r = 0; r < 4; ++r) {
      mrow[mt][r] = -1e30f; lrow[mt][r] = 0.f;
      q_r[mt][r] = qbase + mt * 16 + quad * 4 + r;
    }

  const float scale = 0.07216878364870323f;  // 1/sqrt(192)
  const int nchunk = (q0 + QT) / KC;

  for (int c = 0; c < nchunk; ++c) {
    const int j0 = c * KC;
    const size_t growk = (size_t)b * S_LEN + j0;
    __syncthreads();
    // ---- stage K (bf16, [key][200]) ----
    for (int i = tid; i < 64 * 16; i += 256) {   // nope dims
      const int key = i >> 4, dg = i & 15;
      const float4 v0 = *(const float4*)&kvu[(growk + key) * 4096 + h * 256 + dg * 8];
      const float4 v1 = *(const float4*)&kvu[(growk + key) * 4096 + h * 256 + dg * 8 + 4];
      union { uint4 u; ushort_t s[8]; } pk;
      pk.s[0] = f2bf(v0.x); pk.s[1] = f2bf(v0.y); pk.s[2] = f2bf(v0.z); pk.s[3] = f2bf(v0.w);
      pk.s[4] = f2bf(v1.x); pk.s[5] = f2bf(v1.y); pk.s[6] = f2bf(v1.z); pk.s[7] = f2bf(v1.w);
      *(uint4*)&Kb[key * 200 + dg * 8] = pk.u;
    }
    for (int i = tid; i < 64 * 8; i += 256) {    // rope dims
      const int key = i >> 3, dg = i & 7;
      const float4 v0 = *(const float4*)&krope[(growk + key) * 64 + dg * 8];
      const float4 v1 = *(const float4*)&krope[(growk + key) * 64 + dg * 8 + 4];
      union { uint4 u; ushort_t s[8]; } pk;
      pk.s[0] = f2bf(v0.x); pk.s[1] = f2bf(v0.y); pk.s[2] = f2bf(v0.z); pk.s[3] = f2bf(v0.w);
      pk.s[4] = f2bf(v1.x); pk.s[5] = f2bf(v1.y); pk.s[6] = f2bf(v1.z); pk.s[7] = f2bf(v1.w);
      *(uint4*)&Kb[key * 200 + 128 + dg * 8] = pk.u;
    }
    // ---- stage V transposed (bf16, [vd][72]) ----
    for (int i = tid; i < 64 * 32; i += 256) {
      const int key = i >> 5, vg = i & 31;
      const float4 v = *(const float4*)&kvu[(growk + key) * 4096 + h * 256 + 128 + vg * 4];
      Vt[(vg * 4 + 0) * 72 + key] = f2bf(v.x);
      Vt[(vg * 4 + 1) * 72 + key] = f2bf(v.y);
      Vt[(vg * 4 + 2) * 72 + key] = f2bf(v.z);
      Vt[(vg * 4 + 3) * 72 + key] = f2bf(v.w);
    }
    __syncthreads();

    // ---- QK^T ----
    f32x4 sacc[2][4] = {};
#pragma unroll
    for (int ks = 0; ks < 6; ++ks) {
      short8 kf[4];
#pragma unroll
      for (int kt = 0; kt < 4; ++kt)
        kf[kt] = *(const short8*)&Kb[(kt * 16 + l15) * 200 + ks * 32 + quad * 8];
#pragma unroll
      for (int mt = 0; mt < 2; ++mt)
#pragma unroll
        for (int kt = 0; kt < 4; ++kt)
          sacc[mt][kt] = __builtin_amdgcn_mfma_f32_16x16x32_bf16(qf[mt][ks], kf[kt], sacc[mt][kt], 0, 0, 0);
    }
    // ---- mask + scale (in place) ----
#pragma unroll
    for (int mt = 0; mt < 2; ++mt)
#pragma unroll
      for (int kt = 0; kt < 4; ++kt) {
        const int key = j0 + kt * 16 + l15;
#pragma unroll
        for (int r = 0; r < 4; ++r)
          sacc[mt][kt][r] = (key <= q_r[mt][r]) ? sacc[mt][kt][r] * scale : -1e30f;
      }
    // ---- online softmax (wave-internal, per quad group) ----
    float alpha[2][4];
#pragma unroll
    for (int mt = 0; mt < 2; ++mt)
#pragma unroll
      for (int r = 0; r < 4; ++r) {
        float mx = fmaxf(fmaxf(sacc[mt][0][r], sacc[mt][1][r]),
                         fmaxf(sacc[mt][2][r], sacc[mt][3][r]));
        mx = fmaxf(mx, __shfl_xor(mx, 1));
        mx = fmaxf(mx, __shfl_xor(mx, 2));
        mx = fmaxf(mx, __shfl_xor(mx, 4));
        mx = fmaxf(mx, __shfl_xor(mx, 8));
        const float mn = fmaxf(mrow[mt][r], mx);
        alpha[mt][r] = __expf(mrow[mt][r] - mn);
        mrow[mt][r] = mn;
      }
#pragma unroll
    for (int mt = 0; mt < 2; ++mt)
#pragma unroll
      for (int kt = 0; kt < 4; ++kt)
#pragma unroll
        for (int r = 0; r < 4; ++r)
          sacc[mt][kt][r] = __expf(sacc[mt][kt][r] - mrow[mt][r]);
#pragma unroll
    for (int mt = 0; mt < 2; ++mt)
#pragma unroll
      for (int r = 0; r < 4; ++r) {
        float rs = sacc[mt][0][r] + sacc[mt][1][r] + sacc[mt][2][r] + sacc[mt][3][r];
        rs += __shfl_xor(rs, 1);
        rs += __shfl_xor(rs, 2);
        rs += __shfl_xor(rs, 4);
        rs += __shfl_xor(rs, 8);
        lrow[mt][r] = lrow[mt][r] * alpha[mt][r] + rs;
      }
    // ---- write P (bf16) to per-wave-private LDS ----
#pragma unroll
    for (int mt = 0; mt < 2; ++mt)
#pragma unroll
      for (int kt = 0; kt < 4; ++kt)
#pragma unroll
        for (int r = 0; r < 4; ++r)
          Pb[wq][(mt * 16 + quad * 4 + r) * 72 + kt * 16 + l15] = f2bf(sacc[mt][kt][r]);
    // ---- rescale O ----
#pragma unroll
    for (int mt = 0; mt < 2; ++mt)
#pragma unroll
      for (int nt = 0; nt < 8; ++nt)
#pragma unroll
        for (int r = 0; r < 4; ++r)
          oacc[mt][nt][r] *= alpha[mt][r];
    // ---- PV ----
#pragma unroll
    for (int st = 0; st < 2; ++st) {
      short8 pf[2];
#pragma unroll
      for (int mt = 0; mt < 2; ++mt)
        pf[mt] = *(const short8*)&Pb[wq][(mt * 16 + l15) * 72 + st * 32 + quad * 8];
#pragma unroll
      for (int nt = 0; nt < 8; ++nt) {
        const short8 vf = *(const short8*)&Vt[(nt * 16 + l15) * 72 + st * 32 + quad * 8];
#pragma unroll
        for (int mt = 0; mt < 2; ++mt)
          oacc[mt][nt] = __builtin_amdgcn_mfma_f32_16x16x32_bf16(pf[mt], vf, oacc[mt][nt], 0, 0, 0);
      }
    }
  }

  // ---- store (bf16) ----
#pragma unroll
  for (int mt = 0; mt < 2; ++mt)
#pragma unroll
    for (int r = 0; r < 4; ++r) {
      const float inv = 1.0f / lrow[mt][r];
      const size_t orow = growq + mt * 16 + quad * 4 + r;
#pragma unroll
      for (int nt = 0; nt < 8; ++nt)
        outp[orow * 2048 + h * 128 + nt * 16 + l15] = f2bf(oacc[mt][nt][r] * inv);
    }
}

extern "C" void kernel_launch(void* const* d_in, const int* in_sizes, int n_in,
                              void* d_out, int out_size, void* d_ws, size_t ws_size,
                              hipStream_t stream) {
  const float* x        = (const float*)d_in[0];
  const float* wd_q     = (const float*)d_in[1];
  const float* wu_q     = (const float*)d_in[2];
  const float* q_norm_w = (const float*)d_in[3];
  const float* wd_kv    = (const float*)d_in[4];
  const float* wu_kv    = (const float*)d_in[5];
  const float* kv_norm_w= (const float*)d_in[6];
  const float* wo       = (const float*)d_in[7];
  const float* cosb     = (const float*)d_in[8];
  const float* sinb     = (const float*)d_in[9];
  float* out = (float*)d_out;

  char* ws = (char*)d_ws;
  float*    qall  = (float*)(ws + 0);            // 4096x3072 f32; cq aliases @0
  float*    cq    = (float*)(ws + 0);
  float*    kvu   = (float*)(ws + 50331648);     // 4096x4096 f32
  ushort_t* cqn   = (ushort_t*)(ws + 117440512); // 4096x1536 bf16
  float*    kvd   = (float*)(ws + 130023424);    // 4096x640 f32 (dead after rope)
  ushort_t* ckvn  = (ushort_t*)(ws + 140509184); // 4096x512 bf16 (dead after kvu gemm)
  ushort_t* aoutb = (ushort_t*)(ws + 130023424); // 4096x2048 bf16, aliases kvd+ckvn
  float*    krope = (float*)(ws + 146800640);    // 4096x64 f32
  ushort_t* wdqt  = (ushort_t*)(ws + 147849216); // 1536x2048 bf16
  ushort_t* wdkvt = (ushort_t*)(ws + 154140672); // 640x2048 bf16
  ushort_t* wuqt  = (ushort_t*)(ws + 156762112); // 3072x1536 bf16
  ushort_t* wukvt = (ushort_t*)(ws + 166199296); // 4096x512 bf16
  ushort_t* wot   = (ushort_t*)(ws + 170393600); // 2048x2048 bf16

  const int M = 2 * S_LEN;  // 4096
  dim3 blk(256);

  transpose_cast_k<<<dim3(1536 / 32, 2048 / 32), blk, 0, stream>>>(wd_q, wdqt, 2048, 1536);
  transpose_cast_k<<<dim3(640 / 32, 2048 / 32), blk, 0, stream>>>(wd_kv, wdkvt, 2048, 576);
  transpose_cast_k<<<dim3(3072 / 32, 1536 / 32), blk, 0, stream>>>(wu_q, wuqt, 1536, 3072);
  transpose_cast_k<<<dim3(4096 / 32, 512 / 32), blk, 0, stream>>>(wu_kv, wukvt, 512, 4096);
  transpose_cast_k<<<dim3(2048 / 32, 2048 / 32), blk, 0, stream>>>(wo, wot, 2048, 2048);

  mfma_gemm<true><<<dim3(1536 / 128, M / 128), blk, 0, stream>>>(x, wdqt, cq, M, 1536, 2048, 1536);
  mfma_gemm<true><<<dim3(640 / 128, M / 128), blk, 0, stream>>>(x, wdkvt, kvd, M, 640, 2048, 640);
  rmsnorm_k<<<M, 256, 0, stream>>>(cq, 1536, cqn, 1536, q_norm_w, 1536);
  rmsnorm_k<<<M, 256, 0, stream>>>(kvd, 640, ckvn, 512, kv_norm_w, 512);
  mfma_gemm<false><<<dim3(3072 / 128, M / 128), blk, 0, stream>>>(cqn, wuqt, qall, M, 3072, 1536, 3072);
  mfma_gemm<false><<<dim3(4096 / 128, M / 128), blk, 0, stream>>>(ckvn, wukvt, kvu, M, 4096, 512, 4096);
  rope_k<<<M, 512, 0, stream>>>(qall, kvd, krope, cosb, sinb);
  attn_k<<<2 * NHEAD * (S_LEN / QT), 256, 0, stream>>>(qall, kvu, krope, aoutb);
  mfma_gemm<false><<<dim3(2048 / 128, M / 128), blk, 0, stream>>>(aoutb, wot, out, M, 2048, 2048, 2048);
}